// Round 10
// baseline (144.107 us; speedup 1.0000x reference)
//
#include <hip/hip_runtime.h>
#include <hip/hip_bf16.h>
#include <math.h>

typedef __bf16 bf16_t;
typedef bf16_t bf16x8 __attribute__((ext_vector_type(8)));
typedef bf16_t bf16x4 __attribute__((ext_vector_type(4)));
typedef float  f32x4  __attribute__((ext_vector_type(4)));

#define NB    2
#define SEQ   2048
#define DIM   2048
#define NHEAD 16
#define NKVH  4
#define HDIM  128
#define WINSZ 256
#define KVD   512            // NKVH*HDIM
#define QKVN  3072           // DIM + 2*KVD
#define MROWS 4096           // NB*SEQ

// ---- async global->LDS, 16B per lane, dest = wave-uniform base + lane*16 ----
__device__ __forceinline__ void async_copy16(const void* g, void* lds) {
    __builtin_amdgcn_global_load_lds(
        (const __attribute__((address_space(1))) void*)g,
        (__attribute__((address_space(3))) void*)lds,
        16, 0, 0);
}

// ============================================================================
// Fused preprocessing: x->bf16, 4 weight transposes (f32 [K,N] -> bf16 [N,K]),
// bias concat.  One launch, range-partitioned grid.
// ============================================================================
__global__ __launch_bounds__(256) void preprocess(
    const float* __restrict__ x,  const float* __restrict__ Wq,
    const float* __restrict__ bq, const float* __restrict__ Wk,
    const float* __restrict__ bk, const float* __restrict__ Wv,
    const float* __restrict__ bv, const float* __restrict__ Wo,
    bf16_t* __restrict__ xb, bf16_t* __restrict__ WqkvT,
    bf16_t* __restrict__ WoT, float* __restrict__ bqkv) {
    __shared__ float tile[32][33];
    const int tid = threadIdx.x;
    int bid = blockIdx.x;
    if (bid < 8192) {                       // x -> bf16 (4 elems/thread)
        int i = (bid * 256 + tid) * 4;
        float4 v = *(const float4*)(x + i);
        bf16x4 o;
        o[0] = (bf16_t)v.x; o[1] = (bf16_t)v.y; o[2] = (bf16_t)v.z; o[3] = (bf16_t)v.w;
        *(bf16x4*)(xb + i) = o;
        return;
    }
    bid -= 8192;
    const float* src; bf16_t* dst; int N;
    if (bid < 4096)       { src = Wq; dst = WqkvT;                          N = DIM; }
    else if (bid < 5120)  { src = Wk; dst = WqkvT + (size_t)DIM * DIM;      N = KVD; bid -= 4096; }
    else if (bid < 6144)  { src = Wv; dst = WqkvT + (size_t)(DIM+KVD)*DIM;  N = KVD; bid -= 5120; }
    else if (bid < 10240) { src = Wo; dst = WoT;                            N = DIM; bid -= 6144; }
    else {                                  // bias concat
        int i = (bid - 10240) * 256 + tid;
        if (i < QKVN) {
            float v = (i < DIM) ? bq[i] : ((i < DIM + KVD) ? bk[i - DIM] : bv[i - DIM - KVD]);
            bqkv[i] = v;
        }
        return;
    }
    const int K = DIM;
    int ntile = N / 32;
    int n0 = (bid % ntile) * 32, k0 = (bid / ntile) * 32;
    int tx = tid & 31, ty = tid >> 5;
    for (int r = ty; r < 32; r += 8)
        tile[r][tx] = src[(size_t)(k0 + r) * N + n0 + tx];
    __syncthreads();
    for (int r = ty; r < 32; r += 8)
        dst[(size_t)(n0 + r) * K + k0 + tx] = (bf16_t)tile[tx][r];
}

// ============================================================================
// gemm1b: ONE barrier + ONE vmcnt(0) per BK=64 K-tile (was 2 of each).
// Batch t = both K=32 halves of tile t, staged during tile t-1 into buf t&1;
// the single vmcnt(0)+barrier at tile-t top makes the whole batch visible.
// Within the region: reads-h0 | stage(t+1,h0) | MFMA-h0 | reads-h1 |
// stage(t+1,h1) | MFMA-h1 -- compiler interleaves via counted lgkmcnt
// (reads-h1 overlap MFMA-h0).  stage targets buf^1: never read this tile.
// MPOS = wave rows (MPOS x (8/MPOS) wave grid).  Zero-conflict swizzle kept.
// VFUSE: V-projection columns written directly as blocked V^T tiles.
// ============================================================================
template <int BM, int BN, int MPOS, typename OutT, bool VFUSE>
__global__ __launch_bounds__(512, 1) void gemm1b(const bf16_t* __restrict__ A,
                                                 const bf16_t* __restrict__ Bt,
                                                 const float* __restrict__ bias,
                                                 OutT* __restrict__ C,
                                                 bf16_t* __restrict__ vtb,
                                                 int M, int N, int K, float qs, int qcols) {
    constexpr int NPOS = 8 / MPOS;
    constexpr int ASLOTS = BM / 16;
    constexpr int BSLOTS = BN / 16;
    constexpr int MF = BM / MPOS / 16;
    constexpr int NF = BN / NPOS / 16;
    constexpr int AHALF = BM * 32;
    constexpr int BHALF = BN * 32;
    constexpr int BUFSZ = 2 * (AHALF + BHALF);
    __shared__ bf16_t lds[2 * BUFSZ];

    const int tid  = threadIdx.x;
    const int wave = tid >> 6;
    const int lane = tid & 63;
    const int lg = lane >> 4, lc = lane & 15;
    const int wr = wave / NPOS, wc = wave % NPOS;

    const int nbn  = N / BN;
    const int nblk = (M / BM) * nbn;
    const int qq   = nblk >> 3;
    const int swz  = (blockIdx.x & 7) * qq + (blockIdx.x >> 3);
    const long brow = (long)(swz / nbn) * BM;
    const long bcol = (long)(swz % nbn) * BN;

    f32x4 acc[MF][NF] = {};

    auto stage = [&](int buf, int p, int kt) {
        const int kcol = kt * 64 + p * 32;
        const int srow = lane >> 2;
        const int sch  = lane & 3;
        {
            bf16_t* d = lds + buf * BUFSZ + p * AHALF;
#pragma unroll
            for (int s = wave; s < ASLOTS; s += 8) {
                int row = s * 16 + srow;
                int ch  = sch ^ ((row >> 1) & 3);
                async_copy16(A + (brow + row) * (long)K + kcol + ch * 8, d + s * 512);
            }
        }
        {
            bf16_t* d = lds + buf * BUFSZ + 2 * AHALF + p * BHALF;
#pragma unroll
            for (int s = wave; s < BSLOTS; s += 8) {
                int row = s * 16 + srow;
                int ch  = sch ^ ((row >> 1) & 3);
                async_copy16(Bt + (bcol + row) * (long)K + kcol + ch * 8, d + s * 512);
            }
        }
    };

    stage(0, 0, 0);
    stage(0, 1, 0);

    const int NT = K >> 6;
    const int cswz = (lg ^ ((lc >> 1) & 3)) * 8;
    for (int t = 0; t < NT; ++t) {
        asm volatile("s_waitcnt vmcnt(0)" ::: "memory");   // batch t fully landed
        __builtin_amdgcn_s_barrier();
        asm volatile("" ::: "memory");                     // no read hoists above
        const bf16_t* base = lds + (t & 1) * BUFSZ;
#pragma unroll
        for (int p = 0; p < 2; ++p) {
            const bf16_t* Ab = base + p * AHALF;
            const bf16_t* Bb = base + 2 * AHALF + p * BHALF;
            bf16x8 af[MF], bv[NF];
#pragma unroll
            for (int m = 0; m < MF; ++m)
                af[m] = *(const bf16x8*)(Ab + (wr * (BM / MPOS) + m * 16 + lc) * 32 + cswz);
#pragma unroll
            for (int n = 0; n < NF; ++n)
                bv[n] = *(const bf16x8*)(Bb + (wc * (BN / NPOS) + n * 16 + lc) * 32 + cswz);
            if (t + 1 < NT) stage((t + 1) & 1, p, t + 1);
#pragma unroll
            for (int m = 0; m < MF; ++m)
#pragma unroll
                for (int n = 0; n < NF; ++n)
                    acc[m][n] = __builtin_amdgcn_mfma_f32_16x16x32_bf16(af[m], bv[n], acc[m][n], 0, 0, 0);
        }
    }

#pragma unroll
    for (int n = 0; n < NF; ++n) {
        int gc = (int)bcol + wc * (BN / NPOS) + n * 16 + lc;
        float bvs = bias[gc];
        if constexpr (VFUSE) {
            if (gc >= DIM + KVD) {   // V columns -> blocked V^T tiles
                int vg = (gc - (DIM + KVD)) >> 7;
                int dl = (gc - (DIM + KVD)) & 127;
#pragma unroll
                for (int m = 0; m < MF; ++m) {
                    long gr = brow + wr * (BM / MPOS) + m * 16 + 4 * lg;
                    int bb = (int)(gr >> 11);
                    int js = (int)(gr & (SEQ - 1));
                    bf16x4 ov;
#pragma unroll
                    for (int r = 0; r < 4; ++r) ov[r] = (bf16_t)(acc[m][n][r] + bvs);
                    *(bf16x4*)(vtb + (((size_t)(bb * NKVH) + vg) * 64 + (js >> 5)) * 4096
                                   + dl * 32 + (js & 31)) = ov;
                }
                continue;
            }
        }
        bool ds = gc < qcols;
#pragma unroll
        for (int m = 0; m < MF; ++m) {
            long gr = brow + wr * (BM / MPOS) + m * 16 + 4 * lg;
#pragma unroll
            for (int r = 0; r < 4; ++r) {
                float v = acc[m][n][r] + bvs;
                if (ds) v *= qs;
                C[(gr + r) * (long)N + gc] = (OutT)v;
            }
        }
    }
}

// ============================================================================
// Sliding-window GQA flash attention, QBLK=32, triple-buffered K/V staging
// with counted vmcnt(4) (round-9 measured-best, unchanged).
// ============================================================================
__global__ __launch_bounds__(256) void attn_kernel(const bf16_t* __restrict__ QKV,
                                                   const bf16_t* __restrict__ Vtb,
                                                   bf16_t* __restrict__ Ob) {
    __shared__ bf16_t Kls[3][32 * 128];   // [j][d], chunk^=(row&7)
    __shared__ bf16_t Vls[3][128 * 32];   // [d][j], chunk^=((row^(row>>2))&3)
    __shared__ bf16_t Pls[4][32 * 40];    // per-wave P [q32][j40]

    const int wv   = threadIdx.x >> 6;
    const int lane = threadIdx.x & 63;
    const int lg = lane >> 4, lc = lane & 15;

    const int swb = (blockIdx.x & 7) * 64 + (blockIdx.x >> 3);
    const int ti = swb & 63;
    const int g  = (swb >> 6) & 3;
    const int b  = swb >> 8;
    const int h  = g * 4 + wv;
    const int i0 = ti * 32;
    bf16_t* P = &Pls[wv][0];

    bf16x8 qf[2][4];
#pragma unroll
    for (int sq = 0; sq < 2; ++sq) {
        const bf16_t* qp = QKV + ((size_t)(b * SEQ) + i0 + sq * 16 + lc) * QKVN + h * HDIM + lg * 8;
#pragma unroll
        for (int kk = 0; kk < 4; ++kk) qf[sq][kk] = *(const bf16x8*)(qp + kk * 32);
    }

    auto stage = [&](int buf, int jb) {
        const int j0s = jb * 32;
        const bf16_t* kgb = QKV + ((size_t)(b * SEQ) + j0s) * QKVN + DIM + g * HDIM;
#pragma unroll
        for (int ii = 0; ii < 2; ++ii) {
            int i = wv * 2 + ii;
            int row = i * 4 + (lane >> 4);
            int ch  = (lane & 15) ^ (row & 7);
            async_copy16(kgb + (size_t)row * QKVN + ch * 8, &Kls[buf][i * 512]);
        }
        const bf16_t* vgb = Vtb + (((size_t)(b * NKVH) + g) * 64 + jb) * 4096;
#pragma unroll
        for (int ii = 0; ii < 2; ++ii) {
            int i = wv * 2 + ii;
            int row = i * 16 + (lane >> 2);
            int ch  = (lane & 3) ^ ((row ^ (row >> 2)) & 3);
            async_copy16(vgb + row * 32 + ch * 8, &Vls[buf][i * 512]);
        }
    };

    float m_run[2] = {-1e30f, -1e30f}, l_run[2] = {0.f, 0.f};
    f32x4 oacc[2][8] = {};

    int jlo = i0 - (WINSZ - 1); if (jlo < 0) jlo = 0;
    const int jb0 = jlo >> 5;
    const int jb1 = (i0 + 31) >> 5;

    stage(0, jb0);
    if (jb0 + 1 <= jb1) stage(1, jb0 + 1);

    for (int jb = jb0; jb <= jb1; ++jb) {
        const int j0 = jb * 32;
        const int it = jb - jb0;
        const int cur = it % 3;
        if (jb < jb1) asm volatile("s_waitcnt vmcnt(4)" ::: "memory");
        else          asm volatile("s_waitcnt vmcnt(0)" ::: "memory");
        __builtin_amdgcn_s_barrier();
        asm volatile("" ::: "memory");

        bf16x8 kf[2][4];
#pragma unroll
        for (int t = 0; t < 2; ++t)
#pragma unroll
            for (int kk = 0; kk < 4; ++kk) {
                int row = t * 16 + lc;
                int ch  = (kk * 4 + lg) ^ (row & 7);
                kf[t][kk] = *(const bf16x8*)(&Kls[cur][row * 128 + ch * 8]);
            }
        if (jb + 2 <= jb1) stage((it + 2) % 3, jb + 2);
        asm volatile("s_waitcnt lgkmcnt(0)" ::: "memory");
        __builtin_amdgcn_sched_barrier(0);

        f32x4 s[2][2];
        __builtin_amdgcn_s_setprio(1);
#pragma unroll
        for (int t = 0; t < 2; ++t)
#pragma unroll
            for (int sq = 0; sq < 2; ++sq) {
                f32x4 sv = {};
#pragma unroll
                for (int kk = 0; kk < 4; ++kk)
                    sv = __builtin_amdgcn_mfma_f32_16x16x32_bf16(kf[t][kk], qf[sq][kk], sv, 0, 0, 0);
                s[t][sq] = sv;
            }
        __builtin_amdgcn_s_setprio(0);

        const bool edge = (j0 < i0 - (WINSZ - 32)) || (j0 > i0 - 31);
        if (edge) {
#pragma unroll
            for (int t = 0; t < 2; ++t)
#pragma unroll
                for (int sq = 0; sq < 2; ++sq) {
                    int irow = i0 + sq * 16 + lc;
#pragma unroll
                    for (int r = 0; r < 4; ++r) {
                        int j = j0 + t * 16 + 4 * lg + r;
                        if (j > irow || j < irow - (WINSZ - 1)) s[t][sq][r] = -1e30f;
                    }
                }
        }
        float tmax[2];
#pragma unroll
        for (int sq = 0; sq < 2; ++sq) {
            float tm = fmaxf(fmaxf(fmaxf(s[0][sq][0], s[0][sq][1]), fmaxf(s[0][sq][2], s[0][sq][3])),
                             fmaxf(fmaxf(s[1][sq][0], s[1][sq][1]), fmaxf(s[1][sq][2], s[1][sq][3])));
            tm = fmaxf(tm, __shfl_xor(tm, 16, 64));
            tm = fmaxf(tm, __shfl_xor(tm, 32, 64));
            tmax[sq] = tm;
        }
        if (!__all(tmax[0] - m_run[0] <= 8.0f && tmax[1] - m_run[1] <= 8.0f)) {
#pragma unroll
            for (int sq = 0; sq < 2; ++sq) {
                float m_new = fmaxf(m_run[sq], tmax[sq]);
                float resc = __builtin_amdgcn_exp2f(m_run[sq] - m_new);
                l_run[sq] *= resc;
#pragma unroll
                for (int c = 0; c < 8; ++c) {
                    oacc[sq][c][0] *= resc; oacc[sq][c][1] *= resc;
                    oacc[sq][c][2] *= resc; oacc[sq][c][3] *= resc;
                }
                m_run[sq] = m_new;
            }
        }
        float psum[2] = {0.f, 0.f};
#pragma unroll
        for (int t = 0; t < 2; ++t)
#pragma unroll
            for (int sq = 0; sq < 2; ++sq) {
                bf16x4 pk;
#pragma unroll
                for (int r = 0; r < 4; ++r) {
                    float sv = s[t][sq][r];
                    float p = (edge && sv < -5e29f) ? 0.f : __builtin_amdgcn_exp2f(sv - m_run[sq]);
                    psum[sq] += p;
                    pk[r] = (bf16_t)p;
                }
                *(bf16x4*)(P + (sq * 16 + lc) * 40 + t * 16 + lg * 4) = pk;
            }
#pragma unroll
        for (int sq = 0; sq < 2; ++sq) {
            float ps = psum[sq];
            ps += __shfl_xor(ps, 16, 64);
            ps += __shfl_xor(ps, 32, 64);
            l_run[sq] += ps;
        }
        asm volatile("" ::: "memory");

        bf16x8 vf[8];
#pragma unroll
        for (int c = 0; c < 8; ++c) {
            int row = c * 16 + lc;
            int ch  = lg ^ ((row ^ (row >> 2)) & 3);
            vf[c] = *(const bf16x8*)(&Vls[cur][row * 32 + ch * 8]);
        }
        bf16x8 pf[2];
#pragma unroll
        for (int sq = 0; sq < 2; ++sq)
            pf[sq] = *(const bf16x8*)(P + (sq * 16 + lc) * 40 + lg * 8);

        __builtin_amdgcn_s_setprio(1);
#pragma unroll
        for (int c = 0; c < 8; ++c)
#pragma unroll
            for (int sq = 0; sq < 2; ++sq)
                oacc[sq][c] = __builtin_amdgcn_mfma_f32_16x16x32_bf16(vf[c], pf[sq], oacc[sq][c], 0, 0, 0);
        __builtin_amdgcn_s_setprio(0);
    }

#pragma unroll
    for (int sq = 0; sq < 2; ++sq) {
        const float inv = 1.f / l_run[sq];
#pragma unroll
        for (int c = 0; c < 8; ++c) {
            bf16x4 ov;
#pragma unroll
            for (int r = 0; r < 4; ++r) ov[r] = (bf16_t)(oacc[sq][c][r] * inv);
            *(bf16x4*)(Ob + ((size_t)(b * SEQ) + i0 + sq * 16 + lc) * DIM + h * HDIM + c * 16 + lg * 4) = ov;
        }
    }
}

extern "C" void kernel_launch(void* const* d_in, const int* in_sizes, int n_in,
                              void* d_out, int out_size, void* d_ws, size_t ws_size,
                              hipStream_t stream) {
    const float* x  = (const float*)d_in[0];
    const float* Wq = (const float*)d_in[1];
    const float* bq = (const float*)d_in[2];
    const float* Wk = (const float*)d_in[3];
    const float* bk = (const float*)d_in[4];
    const float* Wv = (const float*)d_in[5];
    const float* bv = (const float*)d_in[6];
    const float* Wo = (const float*)d_in[7];
    const float* bo = (const float*)d_in[8];
    float* out = (float*)d_out;

    char* ws = (char*)d_ws;
    bf16_t* xb    = (bf16_t*)(ws);                       // 16 MB  (later aliased as Ob)
    bf16_t* WqkvT = (bf16_t*)(ws + (16u << 20));         // 12 MB
    bf16_t* WoT   = (bf16_t*)(ws + (28u << 20));         //  8 MB
    bf16_t* QKVb  = (bf16_t*)(ws + (36u << 20));         // 24 MB (V region unused)
    float*  bqkv  = (float*) (ws + (60u << 20));         // 12 KB
    bf16_t* Vtb   = (bf16_t*)(ws + (61u << 20));         //  4 MB blocked V^T
    bf16_t* Ob    = xb;

    const float qs = 0.12751707498038074f;   // 1/sqrt(128) * log2(e)

    preprocess<<<18444, 256, 0, stream>>>(x, Wq, bq, Wk, bk, Wv, bv, Wo,
                                          xb, WqkvT, WoT, bqkv);

    // fused QKV projection: 256x192 tiles, 4x2 wave grid, 1 barrier/K-tile
    gemm1b<256, 192, 4, bf16_t, true><<<dim3((MROWS / 256) * (QKVN / 192)), 512, 0, stream>>>(
        xb, WqkvT, bqkv, QKVb, Vtb, MROWS, QKVN, DIM, qs, DIM);

    attn_kernel<<<dim3(NB * NKVH * (SEQ / 32)), 256, 0, stream>>>(QKVb, Vtb, Ob);

    // output projection: 128x256 tiles, 2x4 wave grid, 1 barrier/K-tile
    gemm1b<128, 256, 2, float, false><<<dim3((MROWS / 128) * (DIM / 256)), 512, 0, stream>>>(
        Ob, WoT, bo, out, nullptr, MROWS, DIM, DIM, 1.0f, 0);
}

// Round 11
// 139.694 us; speedup vs baseline: 1.0316x; 1.0316x over previous
//
#include <hip/hip_runtime.h>
#include <hip/hip_bf16.h>
#include <math.h>

typedef __bf16 bf16_t;
typedef bf16_t bf16x8 __attribute__((ext_vector_type(8)));
typedef bf16_t bf16x4 __attribute__((ext_vector_type(4)));
typedef float  f32x4  __attribute__((ext_vector_type(4)));

#define NB    2
#define SEQ   2048
#define DIM   2048
#define NHEAD 16
#define NKVH  4
#define HDIM  128
#define WINSZ 256
#define KVD   512            // NKVH*HDIM
#define QKVN  3072           // DIM + 2*KVD
#define MROWS 4096           // NB*SEQ

// ---- async global->LDS, 16B per lane, dest = wave-uniform base + lane*16 ----
__device__ __forceinline__ void async_copy16(const void* g, void* lds) {
    __builtin_amdgcn_global_load_lds(
        (const __attribute__((address_space(1))) void*)g,
        (__attribute__((address_space(3))) void*)lds,
        16, 0, 0);
}

// ============================================================================
// Fused preprocessing: x->bf16, 4 weight transposes (f32 [K,N] -> bf16 [N,K]),
// bias concat.  One launch, range-partitioned grid.
// ============================================================================
__global__ __launch_bounds__(256) void preprocess(
    const float* __restrict__ x,  const float* __restrict__ Wq,
    const float* __restrict__ bq, const float* __restrict__ Wk,
    const float* __restrict__ bk, const float* __restrict__ Wv,
    const float* __restrict__ bv, const float* __restrict__ Wo,
    bf16_t* __restrict__ xb, bf16_t* __restrict__ WqkvT,
    bf16_t* __restrict__ WoT, float* __restrict__ bqkv) {
    __shared__ float tile[32][33];
    const int tid = threadIdx.x;
    int bid = blockIdx.x;
    if (bid < 8192) {                       // x -> bf16 (4 elems/thread)
        int i = (bid * 256 + tid) * 4;
        float4 v = *(const float4*)(x + i);
        bf16x4 o;
        o[0] = (bf16_t)v.x; o[1] = (bf16_t)v.y; o[2] = (bf16_t)v.z; o[3] = (bf16_t)v.w;
        *(bf16x4*)(xb + i) = o;
        return;
    }
    bid -= 8192;
    const float* src; bf16_t* dst; int N;
    if (bid < 4096)       { src = Wq; dst = WqkvT;                          N = DIM; }
    else if (bid < 5120)  { src = Wk; dst = WqkvT + (size_t)DIM * DIM;      N = KVD; bid -= 4096; }
    else if (bid < 6144)  { src = Wv; dst = WqkvT + (size_t)(DIM+KVD)*DIM;  N = KVD; bid -= 5120; }
    else if (bid < 10240) { src = Wo; dst = WoT;                            N = DIM; bid -= 6144; }
    else {                                  // bias concat
        int i = (bid - 10240) * 256 + tid;
        if (i < QKVN) {
            float v = (i < DIM) ? bq[i] : ((i < DIM + KVD) ? bk[i - DIM] : bv[i - DIM - KVD]);
            bqkv[i] = v;
        }
        return;
    }
    const int K = DIM;
    int ntile = N / 32;
    int n0 = (bid % ntile) * 32, k0 = (bid / ntile) * 32;
    int tx = tid & 31, ty = tid >> 5;
    for (int r = ty; r < 32; r += 8)
        tile[r][tx] = src[(size_t)(k0 + r) * N + n0 + tx];
    __syncthreads();
    for (int r = ty; r < 32; r += 8)
        dst[(size_t)(n0 + r) * K + k0 + tx] = (bf16_t)tile[tx][r];
}

// ============================================================================
// gemm1b (QKV-best, r10 measured 56.9us): ONE barrier + ONE vmcnt(0) per
// BK=64 tile.  Batch t staged during tile t-1 into buf t&1.  VFUSE writes
// V-projection columns directly as blocked V^T tiles.
// ============================================================================
template <int BM, int BN, int MPOS, typename OutT, bool VFUSE>
__global__ __launch_bounds__(512, 1) void gemm1b(const bf16_t* __restrict__ A,
                                                 const bf16_t* __restrict__ Bt,
                                                 const float* __restrict__ bias,
                                                 OutT* __restrict__ C,
                                                 bf16_t* __restrict__ vtb,
                                                 int M, int N, int K, float qs, int qcols) {
    constexpr int NPOS = 8 / MPOS;
    constexpr int ASLOTS = BM / 16;
    constexpr int BSLOTS = BN / 16;
    constexpr int MF = BM / MPOS / 16;
    constexpr int NF = BN / NPOS / 16;
    constexpr int AHALF = BM * 32;
    constexpr int BHALF = BN * 32;
    constexpr int BUFSZ = 2 * (AHALF + BHALF);
    __shared__ bf16_t lds[2 * BUFSZ];

    const int tid  = threadIdx.x;
    const int wave = tid >> 6;
    const int lane = tid & 63;
    const int lg = lane >> 4, lc = lane & 15;
    const int wr = wave / NPOS, wc = wave % NPOS;

    const int nbn  = N / BN;
    const int nblk = (M / BM) * nbn;
    const int qq   = nblk >> 3;
    const int swz  = (blockIdx.x & 7) * qq + (blockIdx.x >> 3);
    const long brow = (long)(swz / nbn) * BM;
    const long bcol = (long)(swz % nbn) * BN;

    f32x4 acc[MF][NF] = {};

    auto stage = [&](int buf, int p, int kt) {
        const int kcol = kt * 64 + p * 32;
        const int srow = lane >> 2;
        const int sch  = lane & 3;
        {
            bf16_t* d = lds + buf * BUFSZ + p * AHALF;
#pragma unroll
            for (int s = wave; s < ASLOTS; s += 8) {
                int row = s * 16 + srow;
                int ch  = sch ^ ((row >> 1) & 3);
                async_copy16(A + (brow + row) * (long)K + kcol + ch * 8, d + s * 512);
            }
        }
        {
            bf16_t* d = lds + buf * BUFSZ + 2 * AHALF + p * BHALF;
#pragma unroll
            for (int s = wave; s < BSLOTS; s += 8) {
                int row = s * 16 + srow;
                int ch  = sch ^ ((row >> 1) & 3);
                async_copy16(Bt + (bcol + row) * (long)K + kcol + ch * 8, d + s * 512);
            }
        }
    };

    stage(0, 0, 0);
    stage(0, 1, 0);

    const int NT = K >> 6;
    const int cswz = (lg ^ ((lc >> 1) & 3)) * 8;
    for (int t = 0; t < NT; ++t) {
        asm volatile("s_waitcnt vmcnt(0)" ::: "memory");   // batch t fully landed
        __builtin_amdgcn_s_barrier();
        asm volatile("" ::: "memory");                     // no read hoists above
        const bf16_t* base = lds + (t & 1) * BUFSZ;
#pragma unroll
        for (int p = 0; p < 2; ++p) {
            const bf16_t* Ab = base + p * AHALF;
            const bf16_t* Bb = base + 2 * AHALF + p * BHALF;
            bf16x8 af[MF], bv[NF];
#pragma unroll
            for (int m = 0; m < MF; ++m)
                af[m] = *(const bf16x8*)(Ab + (wr * (BM / MPOS) + m * 16 + lc) * 32 + cswz);
#pragma unroll
            for (int n = 0; n < NF; ++n)
                bv[n] = *(const bf16x8*)(Bb + (wc * (BN / NPOS) + n * 16 + lc) * 32 + cswz);
            if (t + 1 < NT) stage((t + 1) & 1, p, t + 1);
#pragma unroll
            for (int m = 0; m < MF; ++m)
#pragma unroll
                for (int n = 0; n < NF; ++n)
                    acc[m][n] = __builtin_amdgcn_mfma_f32_16x16x32_bf16(af[m], bv[n], acc[m][n], 0, 0, 0);
        }
    }

#pragma unroll
    for (int n = 0; n < NF; ++n) {
        int gc = (int)bcol + wc * (BN / NPOS) + n * 16 + lc;
        float bvs = bias[gc];
        if constexpr (VFUSE) {
            if (gc >= DIM + KVD) {   // V columns -> blocked V^T tiles
                int vg = (gc - (DIM + KVD)) >> 7;
                int dl = (gc - (DIM + KVD)) & 127;
#pragma unroll
                for (int m = 0; m < MF; ++m) {
                    long gr = brow + wr * (BM / MPOS) + m * 16 + 4 * lg;
                    int bb = (int)(gr >> 11);
                    int js = (int)(gr & (SEQ - 1));
                    bf16x4 ov;
#pragma unroll
                    for (int r = 0; r < 4; ++r) ov[r] = (bf16_t)(acc[m][n][r] + bvs);
                    *(bf16x4*)(vtb + (((size_t)(bb * NKVH) + vg) * 64 + (js >> 5)) * 4096
                                   + dl * 32 + (js & 31)) = ov;
                }
                continue;
            }
        }
        bool ds = gc < qcols;
#pragma unroll
        for (int m = 0; m < MF; ++m) {
            long gr = brow + wr * (BM / MPOS) + m * 16 + 4 * lg;
#pragma unroll
            for (int r = 0; r < 4; ++r) {
                float v = acc[m][n][r] + bvs;
                if (ds) v *= qs;
                C[(gr + r) * (long)N + gc] = (OutT)v;
            }
        }
    }
}

// ============================================================================
// gemm8p (O-proj-best, r9 measured ~42us): 2-phase-per-K-tile, counted
// vmcnt(miss) keeps one phase of loads in flight across each barrier.
// ============================================================================
template <int BM, int BN, typename OutT>
__global__ __launch_bounds__(512, 1) void gemm8p(const bf16_t* __restrict__ A,
                                                 const bf16_t* __restrict__ Bt,
                                                 const float* __restrict__ bias,
                                                 OutT* __restrict__ C,
                                                 int M, int N, int K, float qs, int qcols) {
    constexpr int ASLOTS = BM / 16;
    constexpr int BSLOTS = BN / 16;
    constexpr int MF   = BM / 32;
    constexpr int NF   = BN / 64;
    constexpr int AHALF = BM * 32;
    constexpr int BHALF = BN * 32;
    constexpr int BUFSZ = 2 * (AHALF + BHALF);
    __shared__ bf16_t lds[2 * BUFSZ];

    const int tid  = threadIdx.x;
    const int wave = tid >> 6;
    const int lane = tid & 63;
    const int lg = lane >> 4, lc = lane & 15;
    const int wr = wave >> 2, wc = wave & 3;

    const int nbn  = N / BN;
    const int nblk = (M / BM) * nbn;
    const int qq   = nblk >> 3;
    const int swz  = (blockIdx.x & 7) * qq + (blockIdx.x >> 3);
    const long brow = (long)(swz / nbn) * BM;
    const long bcol = (long)(swz % nbn) * BN;

    const int aiss = (ASLOTS - wave + 7) >> 3;
    const int biss = (BSLOTS - wave + 7) >> 3;
    const int miss = aiss + biss;

    f32x4 acc[MF][NF] = {};

    auto stage = [&](int buf, int p, int kt) {
        const int kcol = kt * 64 + p * 32;
        const int srow = lane >> 2;
        const int sch  = lane & 3;
        {
            bf16_t* d = lds + buf * BUFSZ + p * AHALF;
#pragma unroll
            for (int s = wave; s < ASLOTS; s += 8) {
                int row = s * 16 + srow;
                int ch  = sch ^ ((row >> 1) & 3);
                async_copy16(A + (brow + row) * (long)K + kcol + ch * 8, d + s * 512);
            }
        }
        {
            bf16_t* d = lds + buf * BUFSZ + 2 * AHALF + p * BHALF;
#pragma unroll
            for (int s = wave; s < BSLOTS; s += 8) {
                int row = s * 16 + srow;
                int ch  = sch ^ ((row >> 1) & 3);
                async_copy16(Bt + (bcol + row) * (long)K + kcol + ch * 8, d + s * 512);
            }
        }
    };

    stage(0, 0, 0);
    stage(0, 1, 0);

    const int NT = K >> 6;
    const int cswz = (lg ^ ((lc >> 1) & 3)) * 8;
    for (int t = 0; t < NT; ++t) {
#pragma unroll
        for (int p = 0; p < 2; ++p) {
            if (t == NT - 1 && p == 1) {
                asm volatile("s_waitcnt vmcnt(0)" ::: "memory");
            } else if (miss == 4) {
                asm volatile("s_waitcnt vmcnt(4)" ::: "memory");
            } else if (miss == 3) {
                asm volatile("s_waitcnt vmcnt(3)" ::: "memory");
            } else {
                asm volatile("s_waitcnt vmcnt(2)" ::: "memory");
            }
            __builtin_amdgcn_s_barrier();
            asm volatile("" ::: "memory");
            const bf16_t* Ab = lds + (t & 1) * BUFSZ + p * AHALF;
            const bf16_t* Bb = lds + (t & 1) * BUFSZ + 2 * AHALF + p * BHALF;
            bf16x8 af[MF], bv[NF];
#pragma unroll
            for (int m = 0; m < MF; ++m)
                af[m] = *(const bf16x8*)(Ab + (wr * (BM / 2) + m * 16 + lc) * 32 + cswz);
#pragma unroll
            for (int n = 0; n < NF; ++n)
                bv[n] = *(const bf16x8*)(Bb + (wc * (BN / 4) + n * 16 + lc) * 32 + cswz);
            if (t + 1 < NT) stage((t + 1) & 1, p, t + 1);
            __builtin_amdgcn_s_setprio(1);
#pragma unroll
            for (int m = 0; m < MF; ++m)
#pragma unroll
                for (int n = 0; n < NF; ++n)
                    acc[m][n] = __builtin_amdgcn_mfma_f32_16x16x32_bf16(af[m], bv[n], acc[m][n], 0, 0, 0);
            __builtin_amdgcn_s_setprio(0);
        }
    }

#pragma unroll
    for (int n = 0; n < NF; ++n) {
        int gc = (int)bcol + wc * (BN / 4) + n * 16 + lc;
        float bvs = bias[gc];
        bool ds = gc < qcols;
#pragma unroll
        for (int m = 0; m < MF; ++m) {
            long gr = brow + wr * (BM / 2) + m * 16 + 4 * lg;
#pragma unroll
            for (int r = 0; r < 4; ++r) {
                float v = acc[m][n][r] + bvs;
                if (ds) v *= qs;
                C[(gr + r) * (long)N + gc] = (OutT)v;
            }
        }
    }
}

// ============================================================================
// Sliding-window GQA flash attention, QBLK=32, triple-buffered K/V staging
// with counted vmcnt(4) (round-9 measured-best, unchanged).
// ============================================================================
__global__ __launch_bounds__(256) void attn_kernel(const bf16_t* __restrict__ QKV,
                                                   const bf16_t* __restrict__ Vtb,
                                                   bf16_t* __restrict__ Ob) {
    __shared__ bf16_t Kls[3][32 * 128];   // [j][d], chunk^=(row&7)
    __shared__ bf16_t Vls[3][128 * 32];   // [d][j], chunk^=((row^(row>>2))&3)
    __shared__ bf16_t Pls[4][32 * 40];    // per-wave P [q32][j40]

    const int wv   = threadIdx.x >> 6;
    const int lane = threadIdx.x & 63;
    const int lg = lane >> 4, lc = lane & 15;

    const int swb = (blockIdx.x & 7) * 64 + (blockIdx.x >> 3);
    const int ti = swb & 63;
    const int g  = (swb >> 6) & 3;
    const int b  = swb >> 8;
    const int h  = g * 4 + wv;
    const int i0 = ti * 32;
    bf16_t* P = &Pls[wv][0];

    bf16x8 qf[2][4];
#pragma unroll
    for (int sq = 0; sq < 2; ++sq) {
        const bf16_t* qp = QKV + ((size_t)(b * SEQ) + i0 + sq * 16 + lc) * QKVN + h * HDIM + lg * 8;
#pragma unroll
        for (int kk = 0; kk < 4; ++kk) qf[sq][kk] = *(const bf16x8*)(qp + kk * 32);
    }

    auto stage = [&](int buf, int jb) {
        const int j0s = jb * 32;
        const bf16_t* kgb = QKV + ((size_t)(b * SEQ) + j0s) * QKVN + DIM + g * HDIM;
#pragma unroll
        for (int ii = 0; ii < 2; ++ii) {
            int i = wv * 2 + ii;
            int row = i * 4 + (lane >> 4);
            int ch  = (lane & 15) ^ (row & 7);
            async_copy16(kgb + (size_t)row * QKVN + ch * 8, &Kls[buf][i * 512]);
        }
        const bf16_t* vgb = Vtb + (((size_t)(b * NKVH) + g) * 64 + jb) * 4096;
#pragma unroll
        for (int ii = 0; ii < 2; ++ii) {
            int i = wv * 2 + ii;
            int row = i * 16 + (lane >> 2);
            int ch  = (lane & 3) ^ ((row ^ (row >> 2)) & 3);
            async_copy16(vgb + row * 32 + ch * 8, &Vls[buf][i * 512]);
        }
    };

    float m_run[2] = {-1e30f, -1e30f}, l_run[2] = {0.f, 0.f};
    f32x4 oacc[2][8] = {};

    int jlo = i0 - (WINSZ - 1); if (jlo < 0) jlo = 0;
    const int jb0 = jlo >> 5;
    const int jb1 = (i0 + 31) >> 5;

    stage(0, jb0);
    if (jb0 + 1 <= jb1) stage(1, jb0 + 1);

    for (int jb = jb0; jb <= jb1; ++jb) {
        const int j0 = jb * 32;
        const int it = jb - jb0;
        const int cur = it % 3;
        if (jb < jb1) asm volatile("s_waitcnt vmcnt(4)" ::: "memory");
        else          asm volatile("s_waitcnt vmcnt(0)" ::: "memory");
        __builtin_amdgcn_s_barrier();
        asm volatile("" ::: "memory");

        bf16x8 kf[2][4];
#pragma unroll
        for (int t = 0; t < 2; ++t)
#pragma unroll
            for (int kk = 0; kk < 4; ++kk) {
                int row = t * 16 + lc;
                int ch  = (kk * 4 + lg) ^ (row & 7);
                kf[t][kk] = *(const bf16x8*)(&Kls[cur][row * 128 + ch * 8]);
            }
        if (jb + 2 <= jb1) stage((it + 2) % 3, jb + 2);
        asm volatile("s_waitcnt lgkmcnt(0)" ::: "memory");
        __builtin_amdgcn_sched_barrier(0);

        f32x4 s[2][2];
        __builtin_amdgcn_s_setprio(1);
#pragma unroll
        for (int t = 0; t < 2; ++t)
#pragma unroll
            for (int sq = 0; sq < 2; ++sq) {
                f32x4 sv = {};
#pragma unroll
                for (int kk = 0; kk < 4; ++kk)
                    sv = __builtin_amdgcn_mfma_f32_16x16x32_bf16(kf[t][kk], qf[sq][kk], sv, 0, 0, 0);
                s[t][sq] = sv;
            }
        __builtin_amdgcn_s_setprio(0);

        const bool edge = (j0 < i0 - (WINSZ - 32)) || (j0 > i0 - 31);
        if (edge) {
#pragma unroll
            for (int t = 0; t < 2; ++t)
#pragma unroll
                for (int sq = 0; sq < 2; ++sq) {
                    int irow = i0 + sq * 16 + lc;
#pragma unroll
                    for (int r = 0; r < 4; ++r) {
                        int j = j0 + t * 16 + 4 * lg + r;
                        if (j > irow || j < irow - (WINSZ - 1)) s[t][sq][r] = -1e30f;
                    }
                }
        }
        float tmax[2];
#pragma unroll
        for (int sq = 0; sq < 2; ++sq) {
            float tm = fmaxf(fmaxf(fmaxf(s[0][sq][0], s[0][sq][1]), fmaxf(s[0][sq][2], s[0][sq][3])),
                             fmaxf(fmaxf(s[1][sq][0], s[1][sq][1]), fmaxf(s[1][sq][2], s[1][sq][3])));
            tm = fmaxf(tm, __shfl_xor(tm, 16, 64));
            tm = fmaxf(tm, __shfl_xor(tm, 32, 64));
            tmax[sq] = tm;
        }
        if (!__all(tmax[0] - m_run[0] <= 8.0f && tmax[1] - m_run[1] <= 8.0f)) {
#pragma unroll
            for (int sq = 0; sq < 2; ++sq) {
                float m_new = fmaxf(m_run[sq], tmax[sq]);
                float resc = __builtin_amdgcn_exp2f(m_run[sq] - m_new);
                l_run[sq] *= resc;
#pragma unroll
                for (int c = 0; c < 8; ++c) {
                    oacc[sq][c][0] *= resc; oacc[sq][c][1] *= resc;
                    oacc[sq][c][2] *= resc; oacc[sq][c][3] *= resc;
                }
                m_run[sq] = m_new;
            }
        }
        float psum[2] = {0.f, 0.f};
#pragma unroll
        for (int t = 0; t < 2; ++t)
#pragma unroll
            for (int sq = 0; sq < 2; ++sq) {
                bf16x4 pk;
#pragma unroll
                for (int r = 0; r < 4; ++r) {
                    float sv = s[t][sq][r];
                    float p = (edge && sv < -5e29f) ? 0.f : __builtin_amdgcn_exp2f(sv - m_run[sq]);
                    psum[sq] += p;
                    pk[r] = (bf16_t)p;
                }
                *(bf16x4*)(P + (sq * 16 + lc) * 40 + t * 16 + lg * 4) = pk;
            }
#pragma unroll
        for (int sq = 0; sq < 2; ++sq) {
            float ps = psum[sq];
            ps += __shfl_xor(ps, 16, 64);
            ps += __shfl_xor(ps, 32, 64);
            l_run[sq] += ps;
        }
        asm volatile("" ::: "memory");

        bf16x8 vf[8];
#pragma unroll
        for (int c = 0; c < 8; ++c) {
            int row = c * 16 + lc;
            int ch  = lg ^ ((row ^ (row >> 2)) & 3);
            vf[c] = *(const bf16x8*)(&Vls[cur][row * 32 + ch * 8]);
        }
        bf16x8 pf[2];
#pragma unroll
        for (int sq = 0; sq < 2; ++sq)
            pf[sq] = *(const bf16x8*)(P + (sq * 16 + lc) * 40 + lg * 8);

        __builtin_amdgcn_s_setprio(1);
#pragma unroll
        for (int c = 0; c < 8; ++c)
#pragma unroll
            for (int sq = 0; sq < 2; ++sq)
                oacc[sq][c] = __builtin_amdgcn_mfma_f32_16x16x32_bf16(vf[c], pf[sq], oacc[sq][c], 0, 0, 0);
        __builtin_amdgcn_s_setprio(0);
    }

#pragma unroll
    for (int sq = 0; sq < 2; ++sq) {
        const float inv = 1.f / l_run[sq];
#pragma unroll
        for (int c = 0; c < 8; ++c) {
            bf16x4 ov;
#pragma unroll
            for (int r = 0; r < 4; ++r) ov[r] = (bf16_t)(oacc[sq][c][r] * inv);
            *(bf16x4*)(Ob + ((size_t)(b * SEQ) + i0 + sq * 16 + lc) * DIM + h * HDIM + c * 16 + lg * 4) = ov;
        }
    }
}

extern "C" void kernel_launch(void* const* d_in, const int* in_sizes, int n_in,
                              void* d_out, int out_size, void* d_ws, size_t ws_size,
                              hipStream_t stream) {
    const float* x  = (const float*)d_in[0];
    const float* Wq = (const float*)d_in[1];
    const float* bq = (const float*)d_in[2];
    const float* Wk = (const float*)d_in[3];
    const float* bk = (const float*)d_in[4];
    const float* Wv = (const float*)d_in[5];
    const float* bv = (const float*)d_in[6];
    const float* Wo = (const float*)d_in[7];
    const float* bo = (const float*)d_in[8];
    float* out = (float*)d_out;

    char* ws = (char*)d_ws;
    bf16_t* xb    = (bf16_t*)(ws);                       // 16 MB  (later aliased as Ob)
    bf16_t* WqkvT = (bf16_t*)(ws + (16u << 20));         // 12 MB
    bf16_t* WoT   = (bf16_t*)(ws + (28u << 20));         //  8 MB
    bf16_t* QKVb  = (bf16_t*)(ws + (36u << 20));         // 24 MB (V region unused)
    float*  bqkv  = (float*) (ws + (60u << 20));         // 12 KB
    bf16_t* Vtb   = (bf16_t*)(ws + (61u << 20));         //  4 MB blocked V^T
    bf16_t* Ob    = xb;

    const float qs = 0.12751707498038074f;   // 1/sqrt(128) * log2(e)

    preprocess<<<18444, 256, 0, stream>>>(x, Wq, bq, Wk, bk, Wv, bv, Wo,
                                          xb, WqkvT, WoT, bqkv);

    // fused QKV projection: 256x192 tiles, 1 barrier/K-tile (r10 best)
    gemm1b<256, 192, 4, bf16_t, true><<<dim3((MROWS / 256) * (QKVN / 192)), 512, 0, stream>>>(
        xb, WqkvT, bqkv, QKVb, Vtb, MROWS, QKVN, DIM, qs, DIM);

    attn_kernel<<<dim3(NB * NKVH * (SEQ / 32)), 256, 0, stream>>>(QKVb, Vtb, Ob);

    // output projection: 128x256 tiles, 2-phase counted vmcnt (r9 best)
    gemm8p<128, 256, float><<<dim3((MROWS / 128) * (DIM / 256)), 512, 0, stream>>>(
        Ob, WoT, bo, out, MROWS, DIM, DIM, 1.0f, 0);
}

// Round 12
// 139.032 us; speedup vs baseline: 1.0365x; 1.0048x over previous
//
#include <hip/hip_runtime.h>
#include <hip/hip_bf16.h>
#include <math.h>

typedef __bf16 bf16_t;
typedef bf16_t bf16x8 __attribute__((ext_vector_type(8)));
typedef bf16_t bf16x4 __attribute__((ext_vector_type(4)));
typedef float  f32x4  __attribute__((ext_vector_type(4)));

#define NB    2
#define SEQ   2048
#define DIM   2048
#define NHEAD 16
#define NKVH  4
#define HDIM  128
#define WINSZ 256
#define KVD   512            // NKVH*HDIM
#define QKVN  3072           // DIM + 2*KVD
#define MROWS 4096           // NB*SEQ

// ---- async global->LDS, 16B per lane, dest = wave-uniform base + lane*16 ----
__device__ __forceinline__ void async_copy16(const void* g, void* lds) {
    __builtin_amdgcn_global_load_lds(
        (const __attribute__((address_space(1))) void*)g,
        (__attribute__((address_space(3))) void*)lds,
        16, 0, 0);
}

// ============================================================================
// Fused preprocessing: x->bf16, 4 weight transposes (f32 [K,N] -> bf16 [N,K]),
// bias concat.  One launch, range-partitioned grid.
// ============================================================================
__global__ __launch_bounds__(256) void preprocess(
    const float* __restrict__ x,  const float* __restrict__ Wq,
    const float* __restrict__ bq, const float* __restrict__ Wk,
    const float* __restrict__ bk, const float* __restrict__ Wv,
    const float* __restrict__ bv, const float* __restrict__ Wo,
    bf16_t* __restrict__ xb, bf16_t* __restrict__ WqkvT,
    bf16_t* __restrict__ WoT, float* __restrict__ bqkv) {
    __shared__ float tile[32][33];
    const int tid = threadIdx.x;
    int bid = blockIdx.x;
    if (bid < 8192) {                       // x -> bf16 (4 elems/thread)
        int i = (bid * 256 + tid) * 4;
        float4 v = *(const float4*)(x + i);
        bf16x4 o;
        o[0] = (bf16_t)v.x; o[1] = (bf16_t)v.y; o[2] = (bf16_t)v.z; o[3] = (bf16_t)v.w;
        *(bf16x4*)(xb + i) = o;
        return;
    }
    bid -= 8192;
    const float* src; bf16_t* dst; int N;
    if (bid < 4096)       { src = Wq; dst = WqkvT;                          N = DIM; }
    else if (bid < 5120)  { src = Wk; dst = WqkvT + (size_t)DIM * DIM;      N = KVD; bid -= 4096; }
    else if (bid < 6144)  { src = Wv; dst = WqkvT + (size_t)(DIM+KVD)*DIM;  N = KVD; bid -= 5120; }
    else if (bid < 10240) { src = Wo; dst = WoT;                            N = DIM; bid -= 6144; }
    else {                                  // bias concat
        int i = (bid - 10240) * 256 + tid;
        if (i < QKVN) {
            float v = (i < DIM) ? bq[i] : ((i < DIM + KVD) ? bk[i - DIM] : bv[i - DIM - KVD]);
            bqkv[i] = v;
        }
        return;
    }
    const int K = DIM;
    int ntile = N / 32;
    int n0 = (bid % ntile) * 32, k0 = (bid / ntile) * 32;
    int tx = tid & 31, ty = tid >> 5;
    for (int r = ty; r < 32; r += 8)
        tile[r][tx] = src[(size_t)(k0 + r) * N + n0 + tx];
    __syncthreads();
    for (int r = ty; r < 32; r += 8)
        dst[(size_t)(n0 + r) * K + k0 + tx] = (bf16_t)tile[tx][r];
}

// ============================================================================
// gemm1b (QKV-best, r10/r11 measured 56us): ONE barrier + ONE vmcnt(0) per
// BK=64 tile, double-buffered.  VFUSE writes V columns as blocked V^T tiles.
// ============================================================================
template <int BM, int BN, int MPOS, typename OutT, bool VFUSE>
__global__ __launch_bounds__(512, 1) void gemm1b(const bf16_t* __restrict__ A,
                                                 const bf16_t* __restrict__ Bt,
                                                 const float* __restrict__ bias,
                                                 OutT* __restrict__ C,
                                                 bf16_t* __restrict__ vtb,
                                                 int M, int N, int K, float qs, int qcols) {
    constexpr int NPOS = 8 / MPOS;
    constexpr int ASLOTS = BM / 16;
    constexpr int BSLOTS = BN / 16;
    constexpr int MF = BM / MPOS / 16;
    constexpr int NF = BN / NPOS / 16;
    constexpr int AHALF = BM * 32;
    constexpr int BHALF = BN * 32;
    constexpr int BUFSZ = 2 * (AHALF + BHALF);
    __shared__ bf16_t lds[2 * BUFSZ];

    const int tid  = threadIdx.x;
    const int wave = tid >> 6;
    const int lane = tid & 63;
    const int lg = lane >> 4, lc = lane & 15;
    const int wr = wave / NPOS, wc = wave % NPOS;

    const int nbn  = N / BN;
    const int nblk = (M / BM) * nbn;
    const int qq   = nblk >> 3;
    const int swz  = (blockIdx.x & 7) * qq + (blockIdx.x >> 3);
    const long brow = (long)(swz / nbn) * BM;
    const long bcol = (long)(swz % nbn) * BN;

    f32x4 acc[MF][NF] = {};

    auto stage = [&](int buf, int p, int kt) {
        const int kcol = kt * 64 + p * 32;
        const int srow = lane >> 2;
        const int sch  = lane & 3;
        {
            bf16_t* d = lds + buf * BUFSZ + p * AHALF;
#pragma unroll
            for (int s = wave; s < ASLOTS; s += 8) {
                int row = s * 16 + srow;
                int ch  = sch ^ ((row >> 1) & 3);
                async_copy16(A + (brow + row) * (long)K + kcol + ch * 8, d + s * 512);
            }
        }
        {
            bf16_t* d = lds + buf * BUFSZ + 2 * AHALF + p * BHALF;
#pragma unroll
            for (int s = wave; s < BSLOTS; s += 8) {
                int row = s * 16 + srow;
                int ch  = sch ^ ((row >> 1) & 3);
                async_copy16(Bt + (bcol + row) * (long)K + kcol + ch * 8, d + s * 512);
            }
        }
    };

    stage(0, 0, 0);
    stage(0, 1, 0);

    const int NT = K >> 6;
    const int cswz = (lg ^ ((lc >> 1) & 3)) * 8;
    for (int t = 0; t < NT; ++t) {
        asm volatile("s_waitcnt vmcnt(0)" ::: "memory");   // batch t fully landed
        __builtin_amdgcn_s_barrier();
        asm volatile("" ::: "memory");                     // no read hoists above
        const bf16_t* base = lds + (t & 1) * BUFSZ;
#pragma unroll
        for (int p = 0; p < 2; ++p) {
            const bf16_t* Ab = base + p * AHALF;
            const bf16_t* Bb = base + 2 * AHALF + p * BHALF;
            bf16x8 af[MF], bv[NF];
#pragma unroll
            for (int m = 0; m < MF; ++m)
                af[m] = *(const bf16x8*)(Ab + (wr * (BM / MPOS) + m * 16 + lc) * 32 + cswz);
#pragma unroll
            for (int n = 0; n < NF; ++n)
                bv[n] = *(const bf16x8*)(Bb + (wc * (BN / NPOS) + n * 16 + lc) * 32 + cswz);
            if (t + 1 < NT) stage((t + 1) & 1, p, t + 1);
#pragma unroll
            for (int m = 0; m < MF; ++m)
#pragma unroll
                for (int n = 0; n < NF; ++n)
                    acc[m][n] = __builtin_amdgcn_mfma_f32_16x16x32_bf16(af[m], bv[n], acc[m][n], 0, 0, 0);
        }
    }

#pragma unroll
    for (int n = 0; n < NF; ++n) {
        int gc = (int)bcol + wc * (BN / NPOS) + n * 16 + lc;
        float bvs = bias[gc];
        if constexpr (VFUSE) {
            if (gc >= DIM + KVD) {   // V columns -> blocked V^T tiles
                int vg = (gc - (DIM + KVD)) >> 7;
                int dl = (gc - (DIM + KVD)) & 127;
#pragma unroll
                for (int m = 0; m < MF; ++m) {
                    long gr = brow + wr * (BM / MPOS) + m * 16 + 4 * lg;
                    int bb = (int)(gr >> 11);
                    int js = (int)(gr & (SEQ - 1));
                    bf16x4 ov;
#pragma unroll
                    for (int r = 0; r < 4; ++r) ov[r] = (bf16_t)(acc[m][n][r] + bvs);
                    *(bf16x4*)(vtb + (((size_t)(bb * NKVH) + vg) * 64 + (js >> 5)) * 4096
                                   + dl * 32 + (js & 31)) = ov;
                }
                continue;
            }
        }
        bool ds = gc < qcols;
#pragma unroll
        for (int m = 0; m < MF; ++m) {
            long gr = brow + wr * (BM / MPOS) + m * 16 + 4 * lg;
#pragma unroll
            for (int r = 0; r < 4; ++r) {
                float v = acc[m][n][r] + bvs;
                if (ds) v *= qs;
                C[(gr + r) * (long)N + gc] = (OutT)v;
            }
        }
    }
}

// ============================================================================
// gemm1b3 (O-proj): gemm1b's 1-barrier/tile + gemm8p's counted vmcnt, via
// TRIPLE buffering (144 KB LDS at 128x256).  Stage batch t+2 during tile t;
// at tile-t top outstanding = batch t+1 (6 issues/wave) -> vmcnt(6) ensures
// batch t landed while t+1 stays in flight; vmcnt(0) only at t=NT-1.
// Target buf (t+2)%3 was last read in tile t-1: complete at this barrier.
// ============================================================================
template <int BM, int BN, int MPOS, typename OutT>
__global__ __launch_bounds__(512, 1) void gemm1b3(const bf16_t* __restrict__ A,
                                                  const bf16_t* __restrict__ Bt,
                                                  const float* __restrict__ bias,
                                                  OutT* __restrict__ C,
                                                  int M, int N, int K, float qs, int qcols) {
    constexpr int NPOS = 8 / MPOS;
    constexpr int ASLOTS = BM / 16;
    constexpr int BSLOTS = BN / 16;
    constexpr int MF = BM / MPOS / 16;
    constexpr int NF = BN / NPOS / 16;
    constexpr int AHALF = BM * 32;
    constexpr int BHALF = BN * 32;
    constexpr int BUFSZ = 2 * (AHALF + BHALF);
    __shared__ bf16_t lds[3 * BUFSZ];

    const int tid  = threadIdx.x;
    const int wave = tid >> 6;
    const int lane = tid & 63;
    const int lg = lane >> 4, lc = lane & 15;
    const int wr = wave / NPOS, wc = wave % NPOS;

    const int nbn  = N / BN;
    const int nblk = (M / BM) * nbn;
    const int qq   = nblk >> 3;
    const int swz  = (blockIdx.x & 7) * qq + (blockIdx.x >> 3);
    const long brow = (long)(swz / nbn) * BM;
    const long bcol = (long)(swz % nbn) * BN;

    const int aiss = (ASLOTS - wave + 7) >> 3;
    const int biss = (BSLOTS - wave + 7) >> 3;
    const int m2   = 2 * (aiss + biss);   // per-wave issues per K-tile batch

    f32x4 acc[MF][NF] = {};

    auto stage = [&](int buf, int p, int kt) {
        const int kcol = kt * 64 + p * 32;
        const int srow = lane >> 2;
        const int sch  = lane & 3;
        {
            bf16_t* d = lds + buf * BUFSZ + p * AHALF;
#pragma unroll
            for (int s = wave; s < ASLOTS; s += 8) {
                int row = s * 16 + srow;
                int ch  = sch ^ ((row >> 1) & 3);
                async_copy16(A + (brow + row) * (long)K + kcol + ch * 8, d + s * 512);
            }
        }
        {
            bf16_t* d = lds + buf * BUFSZ + 2 * AHALF + p * BHALF;
#pragma unroll
            for (int s = wave; s < BSLOTS; s += 8) {
                int row = s * 16 + srow;
                int ch  = sch ^ ((row >> 1) & 3);
                async_copy16(Bt + (bcol + row) * (long)K + kcol + ch * 8, d + s * 512);
            }
        }
    };

    stage(0, 0, 0);
    stage(0, 1, 0);
    stage(1, 0, 1);
    stage(1, 1, 1);

    const int NT = K >> 6;
    const int cswz = (lg ^ ((lc >> 1) & 3)) * 8;
    for (int t = 0; t < NT; ++t) {
        if (t == NT - 1)      asm volatile("s_waitcnt vmcnt(0)" ::: "memory");
        else if (m2 == 6)     asm volatile("s_waitcnt vmcnt(6)" ::: "memory");
        else if (m2 == 8)     asm volatile("s_waitcnt vmcnt(8)" ::: "memory");
        else                  asm volatile("s_waitcnt vmcnt(4)" ::: "memory");
        __builtin_amdgcn_s_barrier();
        asm volatile("" ::: "memory");
        const bf16_t* base = lds + (t % 3) * BUFSZ;
#pragma unroll
        for (int p = 0; p < 2; ++p) {
            const bf16_t* Ab = base + p * AHALF;
            const bf16_t* Bb = base + 2 * AHALF + p * BHALF;
            bf16x8 af[MF], bv[NF];
#pragma unroll
            for (int m = 0; m < MF; ++m)
                af[m] = *(const bf16x8*)(Ab + (wr * (BM / MPOS) + m * 16 + lc) * 32 + cswz);
#pragma unroll
            for (int n = 0; n < NF; ++n)
                bv[n] = *(const bf16x8*)(Bb + (wc * (BN / NPOS) + n * 16 + lc) * 32 + cswz);
            if (t + 2 < NT) stage((t + 2) % 3, p, t + 2);
#pragma unroll
            for (int m = 0; m < MF; ++m)
#pragma unroll
                for (int n = 0; n < NF; ++n)
                    acc[m][n] = __builtin_amdgcn_mfma_f32_16x16x32_bf16(af[m], bv[n], acc[m][n], 0, 0, 0);
        }
    }

#pragma unroll
    for (int n = 0; n < NF; ++n) {
        int gc = (int)bcol + wc * (BN / NPOS) + n * 16 + lc;
        float bvs = bias[gc];
        bool ds = gc < qcols;
#pragma unroll
        for (int m = 0; m < MF; ++m) {
            long gr = brow + wr * (BM / MPOS) + m * 16 + 4 * lg;
#pragma unroll
            for (int r = 0; r < 4; ++r) {
                float v = acc[m][n][r] + bvs;
                if (ds) v *= qs;
                C[(gr + r) * (long)N + gc] = (OutT)v;
            }
        }
    }
}

// ============================================================================
// Sliding-window GQA flash attention, 8 waves/block = 4 heads x 2 q-groups
// (QBLK=64): K/V staged once per block (halved again vs QBLK=32), tribuf,
// counted vmcnt(2).  Per-wave numerics identical to the r9-verified kernel;
// wholly-masked tiles for the upper q-group are handled by the existing
// (edge && sv<-5e29) -> p=0 guard.
// ============================================================================
__global__ __launch_bounds__(512) void attn_kernel(const bf16_t* __restrict__ QKV,
                                                   const bf16_t* __restrict__ Vtb,
                                                   bf16_t* __restrict__ Ob) {
    __shared__ bf16_t Kls[3][32 * 128];   // [j][d], chunk^=(row&7)
    __shared__ bf16_t Vls[3][128 * 32];   // [d][j], chunk^=((row^(row>>2))&3)
    __shared__ bf16_t Pls[8][32 * 40];    // per-wave P [q32][j40]

    const int wv   = threadIdx.x >> 6;    // 0..7
    const int lane = threadIdx.x & 63;
    const int lg = lane >> 4, lc = lane & 15;
    const int wg = wv >> 2;               // q-group (0: rows 0-31, 1: rows 32-63)
    const int hh = wv & 3;                // head within KV group

    // bijective XCD swizzle: 256 blocks -> 32 per XCD
    const int swb = (blockIdx.x & 7) * 32 + (blockIdx.x >> 3);
    const int ti = swb & 31;
    const int g  = (swb >> 5) & 3;
    const int b  = swb >> 7;
    const int h  = g * 4 + hh;
    const int i0b = ti * 64;              // block q base
    const int i0  = i0b + wg * 32;        // wave q base
    bf16_t* P = &Pls[wv][0];

    bf16x8 qf[2][4];
#pragma unroll
    for (int sq = 0; sq < 2; ++sq) {
        const bf16_t* qp = QKV + ((size_t)(b * SEQ) + i0 + sq * 16 + lc) * QKVN + h * HDIM + lg * 8;
#pragma unroll
        for (int kk = 0; kk < 4; ++kk) qf[sq][kk] = *(const bf16x8*)(qp + kk * 32);
    }

    auto stage = [&](int buf, int jb) {
        const bf16_t* kgb = QKV + ((size_t)(b * SEQ) + jb * 32) * QKVN + DIM + g * HDIM;
        {
            int row = wv * 4 + (lane >> 4);
            int ch  = (lane & 15) ^ (row & 7);
            async_copy16(kgb + (size_t)row * QKVN + ch * 8, &Kls[buf][wv * 512]);
        }
        const bf16_t* vgb = Vtb + (((size_t)(b * NKVH) + g) * 64 + jb) * 4096;
        {
            int row = wv * 16 + (lane >> 2);
            int ch  = (lane & 3) ^ ((row ^ (row >> 2)) & 3);
            async_copy16(vgb + row * 32 + ch * 8, &Vls[buf][wv * 512]);
        }
    };

    float m_run[2] = {-1e30f, -1e30f}, l_run[2] = {0.f, 0.f};
    f32x4 oacc[2][8] = {};

    int jlo = i0b - (WINSZ - 1); if (jlo < 0) jlo = 0;
    const int jb0 = jlo >> 5;
    const int jb1 = (i0b + 63) >> 5;

    stage(0, jb0);
    if (jb0 + 1 <= jb1) stage(1, jb0 + 1);

    for (int jb = jb0; jb <= jb1; ++jb) {
        const int j0 = jb * 32;
        const int it = jb - jb0;
        const int cur = it % 3;
        if (jb < jb1) asm volatile("s_waitcnt vmcnt(2)" ::: "memory");
        else          asm volatile("s_waitcnt vmcnt(0)" ::: "memory");
        __builtin_amdgcn_s_barrier();
        asm volatile("" ::: "memory");

        bf16x8 kf[2][4];
#pragma unroll
        for (int t = 0; t < 2; ++t)
#pragma unroll
            for (int kk = 0; kk < 4; ++kk) {
                int row = t * 16 + lc;
                int ch  = (kk * 4 + lg) ^ (row & 7);
                kf[t][kk] = *(const bf16x8*)(&Kls[cur][row * 128 + ch * 8]);
            }
        if (jb + 2 <= jb1) stage((it + 2) % 3, jb + 2);
        asm volatile("s_waitcnt lgkmcnt(0)" ::: "memory");
        __builtin_amdgcn_sched_barrier(0);

        f32x4 s[2][2];
        __builtin_amdgcn_s_setprio(1);
#pragma unroll
        for (int t = 0; t < 2; ++t)
#pragma unroll
            for (int sq = 0; sq < 2; ++sq) {
                f32x4 sv = {};
#pragma unroll
                for (int kk = 0; kk < 4; ++kk)
                    sv = __builtin_amdgcn_mfma_f32_16x16x32_bf16(kf[t][kk], qf[sq][kk], sv, 0, 0, 0);
                s[t][sq] = sv;
            }
        __builtin_amdgcn_s_setprio(0);

        const bool edge = (j0 < i0 - (WINSZ - 32)) || (j0 > i0 - 31);
        if (edge) {
#pragma unroll
            for (int t = 0; t < 2; ++t)
#pragma unroll
                for (int sq = 0; sq < 2; ++sq) {
                    int irow = i0 + sq * 16 + lc;
#pragma unroll
                    for (int r = 0; r < 4; ++r) {
                        int j = j0 + t * 16 + 4 * lg + r;
                        if (j > irow || j < irow - (WINSZ - 1)) s[t][sq][r] = -1e30f;
                    }
                }
        }
        float tmax[2];
#pragma unroll
        for (int sq = 0; sq < 2; ++sq) {
            float tm = fmaxf(fmaxf(fmaxf(s[0][sq][0], s[0][sq][1]), fmaxf(s[0][sq][2], s[0][sq][3])),
                             fmaxf(fmaxf(s[1][sq][0], s[1][sq][1]), fmaxf(s[1][sq][2], s[1][sq][3])));
            tm = fmaxf(tm, __shfl_xor(tm, 16, 64));
            tm = fmaxf(tm, __shfl_xor(tm, 32, 64));
            tmax[sq] = tm;
        }
        if (!__all(tmax[0] - m_run[0] <= 8.0f && tmax[1] - m_run[1] <= 8.0f)) {
#pragma unroll
            for (int sq = 0; sq < 2; ++sq) {
                float m_new = fmaxf(m_run[sq], tmax[sq]);
                float resc = __builtin_amdgcn_exp2f(m_run[sq] - m_new);
                l_run[sq] *= resc;
#pragma unroll
                for (int c = 0; c < 8; ++c) {
                    oacc[sq][c][0] *= resc; oacc[sq][c][1] *= resc;
                    oacc[sq][c][2] *= resc; oacc[sq][c][3] *= resc;
                }
                m_run[sq] = m_new;
            }
        }
        float psum[2] = {0.f, 0.f};
#pragma unroll
        for (int t = 0; t < 2; ++t)
#pragma unroll
            for (int sq = 0; sq < 2; ++sq) {
                bf16x4 pk;
#pragma unroll
                for (int r = 0; r < 4; ++r) {
                    float sv = s[t][sq][r];
                    float p = (edge && sv < -5e29f) ? 0.f : __builtin_amdgcn_exp2f(sv - m_run[sq]);
                    psum[sq] += p;
                    pk[r] = (bf16_t)p;
                }
                *(bf16x4*)(P + (sq * 16 + lc) * 40 + t * 16 + lg * 4) = pk;
            }
#pragma unroll
        for (int sq = 0; sq < 2; ++sq) {
            float ps = psum[sq];
            ps += __shfl_xor(ps, 16, 64);
            ps += __shfl_xor(ps, 32, 64);
            l_run[sq] += ps;
        }
        asm volatile("" ::: "memory");

        bf16x8 vf[8];
#pragma unroll
        for (int c = 0; c < 8; ++c) {
            int row = c * 16 + lc;
            int ch  = lg ^ ((row ^ (row >> 2)) & 3);
            vf[c] = *(const bf16x8*)(&Vls[cur][row * 32 + ch * 8]);
        }
        bf16x8 pf[2];
#pragma unroll
        for (int sq = 0; sq < 2; ++sq)
            pf[sq] = *(const bf16x8*)(P + (sq * 16 + lc) * 40 + lg * 8);

        __builtin_amdgcn_s_setprio(1);
#pragma unroll
        for (int c = 0; c < 8; ++c)
#pragma unroll
            for (int sq = 0; sq < 2; ++sq)
                oacc[sq][c] = __builtin_amdgcn_mfma_f32_16x16x32_bf16(vf[c], pf[sq], oacc[sq][c], 0, 0, 0);
        __builtin_amdgcn_s_setprio(0);
    }

#pragma unroll
    for (int sq = 0; sq < 2; ++sq) {
        const float inv = 1.f / l_run[sq];
#pragma unroll
        for (int c = 0; c < 8; ++c) {
            bf16x4 ov;
#pragma unroll
            for (int r = 0; r < 4; ++r) ov[r] = (bf16_t)(oacc[sq][c][r] * inv);
            *(bf16x4*)(Ob + ((size_t)(b * SEQ) + i0 + sq * 16 + lc) * DIM + h * HDIM + c * 16 + lg * 4) = ov;
        }
    }
}

extern "C" void kernel_launch(void* const* d_in, const int* in_sizes, int n_in,
                              void* d_out, int out_size, void* d_ws, size_t ws_size,
                              hipStream_t stream) {
    const float* x  = (const float*)d_in[0];
    const float* Wq = (const float*)d_in[1];
    const float* bq = (const float*)d_in[2];
    const float* Wk = (const float*)d_in[3];
    const float* bk = (const float*)d_in[4];
    const float* Wv = (const float*)d_in[5];
    const float* bv = (const float*)d_in[6];
    const float* Wo = (const float*)d_in[7];
    const float* bo = (const float*)d_in[8];
    float* out = (float*)d_out;

    char* ws = (char*)d_ws;
    bf16_t* xb    = (bf16_t*)(ws);                       // 16 MB  (later aliased as Ob)
    bf16_t* WqkvT = (bf16_t*)(ws + (16u << 20));         // 12 MB
    bf16_t* WoT   = (bf16_t*)(ws + (28u << 20));         //  8 MB
    bf16_t* QKVb  = (bf16_t*)(ws + (36u << 20));         // 24 MB (V region unused)
    float*  bqkv  = (float*) (ws + (60u << 20));         // 12 KB
    bf16_t* Vtb   = (bf16_t*)(ws + (61u << 20));         //  4 MB blocked V^T
    bf16_t* Ob    = xb;

    const float qs = 0.12751707498038074f;   // 1/sqrt(128) * log2(e)

    preprocess<<<18444, 256, 0, stream>>>(x, Wq, bq, Wk, bk, Wv, bv, Wo,
                                          xb, WqkvT, WoT, bqkv);

    // fused QKV projection: 256x192 tiles, 1 barrier/K-tile, dbuf (r10 best)
    gemm1b<256, 192, 4, bf16_t, true><<<dim3((MROWS / 256) * (QKVN / 192)), 512, 0, stream>>>(
        xb, WqkvT, bqkv, QKVb, Vtb, MROWS, QKVN, DIM, qs, DIM);

    attn_kernel<<<dim3(NB * NKVH * (SEQ / 64)), 512, 0, stream>>>(QKVb, Vtb, Ob);

    // output projection: 128x256 tiles, 1 barrier/K-tile, tribuf counted vmcnt
    gemm1b3<128, 256, 2, float><<<dim3((MROWS / 128) * (DIM / 256)), 512, 0, stream>>>(
        Ob, WoT, bo, out, MROWS, DIM, DIM, 1.0f, 0);
}

// Round 14
// 138.944 us; speedup vs baseline: 1.0372x; 1.0006x over previous
//
#include <hip/hip_runtime.h>
#include <hip/hip_bf16.h>
#include <math.h>

typedef __bf16 bf16_t;
typedef bf16_t bf16x8 __attribute__((ext_vector_type(8)));
typedef bf16_t bf16x4 __attribute__((ext_vector_type(4)));
typedef float  f32x4  __attribute__((ext_vector_type(4)));

#define NB    2
#define SEQ   2048
#define DIM   2048
#define NHEAD 16
#define NKVH  4
#define HDIM  128
#define WINSZ 256
#define KVD   512            // NKVH*HDIM
#define QKVN  3072           // DIM + 2*KVD
#define MROWS 4096           // NB*SEQ

// ---- async global->LDS, 16B per lane, dest = wave-uniform base + lane*16 ----
__device__ __forceinline__ void async_copy16(const void* g, void* lds) {
    __builtin_amdgcn_global_load_lds(
        (const __attribute__((address_space(1))) void*)g,
        (__attribute__((address_space(3))) void*)lds,
        16, 0, 0);
}

// ============================================================================
// Fused preprocessing: x->bf16, 4 weight transposes (f32 [K,N] -> bf16 [N,K]),
// bias concat.  One launch, range-partitioned grid.
// ============================================================================
__global__ __launch_bounds__(256) void preprocess(
    const float* __restrict__ x,  const float* __restrict__ Wq,
    const float* __restrict__ bq, const float* __restrict__ Wk,
    const float* __restrict__ bk, const float* __restrict__ Wv,
    const float* __restrict__ bv, const float* __restrict__ Wo,
    bf16_t* __restrict__ xb, bf16_t* __restrict__ WqkvT,
    bf16_t* __restrict__ WoT, float* __restrict__ bqkv) {
    __shared__ float tile[32][33];
    const int tid = threadIdx.x;
    int bid = blockIdx.x;
    if (bid < 8192) {                       // x -> bf16 (4 elems/thread)
        int i = (bid * 256 + tid) * 4;
        float4 v = *(const float4*)(x + i);
        bf16x4 o;
        o[0] = (bf16_t)v.x; o[1] = (bf16_t)v.y; o[2] = (bf16_t)v.z; o[3] = (bf16_t)v.w;
        *(bf16x4*)(xb + i) = o;
        return;
    }
    bid -= 8192;
    const float* src; bf16_t* dst; int N;
    if (bid < 4096)       { src = Wq; dst = WqkvT;                          N = DIM; }
    else if (bid < 5120)  { src = Wk; dst = WqkvT + (size_t)DIM * DIM;      N = KVD; bid -= 4096; }
    else if (bid < 6144)  { src = Wv; dst = WqkvT + (size_t)(DIM+KVD)*DIM;  N = KVD; bid -= 5120; }
    else if (bid < 10240) { src = Wo; dst = WoT;                            N = DIM; bid -= 6144; }
    else {                                  // bias concat
        int i = (bid - 10240) * 256 + tid;
        if (i < QKVN) {
            float v = (i < DIM) ? bq[i] : ((i < DIM + KVD) ? bk[i - DIM] : bv[i - DIM - KVD]);
            bqkv[i] = v;
        }
        return;
    }
    const int K = DIM;
    int ntile = N / 32;
    int n0 = (bid % ntile) * 32, k0 = (bid / ntile) * 32;
    int tx = tid & 31, ty = tid >> 5;
    for (int r = ty; r < 32; r += 8)
        tile[r][tx] = src[(size_t)(k0 + r) * N + n0 + tx];
    __syncthreads();
    for (int r = ty; r < 32; r += 8)
        dst[(size_t)(n0 + r) * K + k0 + tx] = (bf16_t)tile[tx][r];
}

// ============================================================================
// gemm1b (QKV-best, r10-r12 measured 56us): ONE barrier + ONE vmcnt(0) per
// BK=64 tile, double-buffered.  VFUSE writes V columns as blocked V^T tiles.
// ============================================================================
template <int BM, int BN, int MPOS, typename OutT, bool VFUSE>
__global__ __launch_bounds__(512, 1) void gemm1b(const bf16_t* __restrict__ A,
                                                 const bf16_t* __restrict__ Bt,
                                                 const float* __restrict__ bias,
                                                 OutT* __restrict__ C,
                                                 bf16_t* __restrict__ vtb,
                                                 int M, int N, int K, float qs, int qcols) {
    constexpr int NPOS = 8 / MPOS;
    constexpr int ASLOTS = BM / 16;
    constexpr int BSLOTS = BN / 16;
    constexpr int MF = BM / MPOS / 16;
    constexpr int NF = BN / NPOS / 16;
    constexpr int AHALF = BM * 32;
    constexpr int BHALF = BN * 32;
    constexpr int BUFSZ = 2 * (AHALF + BHALF);
    __shared__ bf16_t lds[2 * BUFSZ];

    const int tid  = threadIdx.x;
    const int wave = tid >> 6;
    const int lane = tid & 63;
    const int lg = lane >> 4, lc = lane & 15;
    const int wr = wave / NPOS, wc = wave % NPOS;

    const int nbn  = N / BN;
    const int nblk = (M / BM) * nbn;
    const int qq   = nblk >> 3;
    const int swz  = (blockIdx.x & 7) * qq + (blockIdx.x >> 3);
    const long brow = (long)(swz / nbn) * BM;
    const long bcol = (long)(swz % nbn) * BN;

    f32x4 acc[MF][NF] = {};

    auto stage = [&](int buf, int p, int kt) {
        const int kcol = kt * 64 + p * 32;
        const int srow = lane >> 2;
        const int sch  = lane & 3;
        {
            bf16_t* d = lds + buf * BUFSZ + p * AHALF;
#pragma unroll
            for (int s = wave; s < ASLOTS; s += 8) {
                int row = s * 16 + srow;
                int ch  = sch ^ ((row >> 1) & 3);
                async_copy16(A + (brow + row) * (long)K + kcol + ch * 8, d + s * 512);
            }
        }
        {
            bf16_t* d = lds + buf * BUFSZ + 2 * AHALF + p * BHALF;
#pragma unroll
            for (int s = wave; s < BSLOTS; s += 8) {
                int row = s * 16 + srow;
                int ch  = sch ^ ((row >> 1) & 3);
                async_copy16(Bt + (bcol + row) * (long)K + kcol + ch * 8, d + s * 512);
            }
        }
    };

    stage(0, 0, 0);
    stage(0, 1, 0);

    const int NT = K >> 6;
    const int cswz = (lg ^ ((lc >> 1) & 3)) * 8;
    for (int t = 0; t < NT; ++t) {
        asm volatile("s_waitcnt vmcnt(0)" ::: "memory");   // batch t fully landed
        __builtin_amdgcn_s_barrier();
        asm volatile("" ::: "memory");                     // no read hoists above
        const bf16_t* base = lds + (t & 1) * BUFSZ;
#pragma unroll
        for (int p = 0; p < 2; ++p) {
            const bf16_t* Ab = base + p * AHALF;
            const bf16_t* Bb = base + 2 * AHALF + p * BHALF;
            bf16x8 af[MF], bv[NF];
#pragma unroll
            for (int m = 0; m < MF; ++m)
                af[m] = *(const bf16x8*)(Ab + (wr * (BM / MPOS) + m * 16 + lc) * 32 + cswz);
#pragma unroll
            for (int n = 0; n < NF; ++n)
                bv[n] = *(const bf16x8*)(Bb + (wc * (BN / NPOS) + n * 16 + lc) * 32 + cswz);
            if (t + 1 < NT) stage((t + 1) & 1, p, t + 1);
#pragma unroll
            for (int m = 0; m < MF; ++m)
#pragma unroll
                for (int n = 0; n < NF; ++n)
                    acc[m][n] = __builtin_amdgcn_mfma_f32_16x16x32_bf16(af[m], bv[n], acc[m][n], 0, 0, 0);
        }
    }

#pragma unroll
    for (int n = 0; n < NF; ++n) {
        int gc = (int)bcol + wc * (BN / NPOS) + n * 16 + lc;
        float bvs = bias[gc];
        if constexpr (VFUSE) {
            if (gc >= DIM + KVD) {   // V columns -> blocked V^T tiles
                int vg = (gc - (DIM + KVD)) >> 7;
                int dl = (gc - (DIM + KVD)) & 127;
#pragma unroll
                for (int m = 0; m < MF; ++m) {
                    long gr = brow + wr * (BM / MPOS) + m * 16 + 4 * lg;
                    int bb = (int)(gr >> 11);
                    int js = (int)(gr & (SEQ - 1));
                    bf16x4 ov;
#pragma unroll
                    for (int r = 0; r < 4; ++r) ov[r] = (bf16_t)(acc[m][n][r] + bvs);
                    *(bf16x4*)(vtb + (((size_t)(bb * NKVH) + vg) * 64 + (js >> 5)) * 4096
                                   + dl * 32 + (js & 31)) = ov;
                }
                continue;
            }
        }
        bool ds = gc < qcols;
#pragma unroll
        for (int m = 0; m < MF; ++m) {
            long gr = brow + wr * (BM / MPOS) + m * 16 + 4 * lg;
#pragma unroll
            for (int r = 0; r < 4; ++r) {
                float v = acc[m][n][r] + bvs;
                if (ds) v *= qs;
                C[(gr + r) * (long)N + gc] = (OutT)v;
            }
        }
    }
}

// ============================================================================
// gemm1b3 (O-proj, r11/r12 measured): 1 barrier/K-tile + counted vmcnt via
// triple buffering (144 KB LDS at 128x256).  Stage batch t+2 during tile t;
// vmcnt(6) at tile-t top ensures batch t landed while t+1 stays in flight.
// ============================================================================
template <int BM, int BN, int MPOS, typename OutT>
__global__ __launch_bounds__(512, 1) void gemm1b3(const bf16_t* __restrict__ A,
                                                  const bf16_t* __restrict__ Bt,
                                                  const float* __restrict__ bias,
                                                  OutT* __restrict__ C,
                                                  int M, int N, int K, float qs, int qcols) {
    constexpr int NPOS = 8 / MPOS;
    constexpr int ASLOTS = BM / 16;
    constexpr int BSLOTS = BN / 16;
    constexpr int MF = BM / MPOS / 16;
    constexpr int NF = BN / NPOS / 16;
    constexpr int AHALF = BM * 32;
    constexpr int BHALF = BN * 32;
    constexpr int BUFSZ = 2 * (AHALF + BHALF);
    __shared__ bf16_t lds[3 * BUFSZ];

    const int tid  = threadIdx.x;
    const int wave = tid >> 6;
    const int lane = tid & 63;
    const int lg = lane >> 4, lc = lane & 15;
    const int wr = wave / NPOS, wc = wave % NPOS;

    const int nbn  = N / BN;
    const int nblk = (M / BM) * nbn;
    const int qq   = nblk >> 3;
    const int swz  = (blockIdx.x & 7) * qq + (blockIdx.x >> 3);
    const long brow = (long)(swz / nbn) * BM;
    const long bcol = (long)(swz % nbn) * BN;

    const int aiss = (ASLOTS - wave + 7) >> 3;
    const int biss = (BSLOTS - wave + 7) >> 3;
    const int m2   = 2 * (aiss + biss);

    f32x4 acc[MF][NF] = {};

    auto stage = [&](int buf, int p, int kt) {
        const int kcol = kt * 64 + p * 32;
        const int srow = lane >> 2;
        const int sch  = lane & 3;
        {
            bf16_t* d = lds + buf * BUFSZ + p * AHALF;
#pragma unroll
            for (int s = wave; s < ASLOTS; s += 8) {
                int row = s * 16 + srow;
                int ch  = sch ^ ((row >> 1) & 3);
                async_copy16(A + (brow + row) * (long)K + kcol + ch * 8, d + s * 512);
            }
        }
        {
            bf16_t* d = lds + buf * BUFSZ + 2 * AHALF + p * BHALF;
#pragma unroll
            for (int s = wave; s < BSLOTS; s += 8) {
                int row = s * 16 + srow;
                int ch  = sch ^ ((row >> 1) & 3);
                async_copy16(Bt + (bcol + row) * (long)K + kcol + ch * 8, d + s * 512);
            }
        }
    };

    stage(0, 0, 0);
    stage(0, 1, 0);
    stage(1, 0, 1);
    stage(1, 1, 1);

    const int NT = K >> 6;
    const int cswz = (lg ^ ((lc >> 1) & 3)) * 8;
    for (int t = 0; t < NT; ++t) {
        if (t == NT - 1)      asm volatile("s_waitcnt vmcnt(0)" ::: "memory");
        else if (m2 == 6)     asm volatile("s_waitcnt vmcnt(6)" ::: "memory");
        else if (m2 == 8)     asm volatile("s_waitcnt vmcnt(8)" ::: "memory");
        else                  asm volatile("s_waitcnt vmcnt(4)" ::: "memory");
        __builtin_amdgcn_s_barrier();
        asm volatile("" ::: "memory");
        const bf16_t* base = lds + (t % 3) * BUFSZ;
#pragma unroll
        for (int p = 0; p < 2; ++p) {
            const bf16_t* Ab = base + p * AHALF;
            const bf16_t* Bb = base + 2 * AHALF + p * BHALF;
            bf16x8 af[MF], bv[NF];
#pragma unroll
            for (int m = 0; m < MF; ++m)
                af[m] = *(const bf16x8*)(Ab + (wr * (BM / MPOS) + m * 16 + lc) * 32 + cswz);
#pragma unroll
            for (int n = 0; n < NF; ++n)
                bv[n] = *(const bf16x8*)(Bb + (wc * (BN / NPOS) + n * 16 + lc) * 32 + cswz);
            if (t + 2 < NT) stage((t + 2) % 3, p, t + 2);
#pragma unroll
            for (int m = 0; m < MF; ++m)
#pragma unroll
                for (int n = 0; n < NF; ++n)
                    acc[m][n] = __builtin_amdgcn_mfma_f32_16x16x32_bf16(af[m], bv[n], acc[m][n], 0, 0, 0);
        }
    }

#pragma unroll
    for (int n = 0; n < NF; ++n) {
        int gc = (int)bcol + wc * (BN / NPOS) + n * 16 + lc;
        float bvs = bias[gc];
        bool ds = gc < qcols;
#pragma unroll
        for (int m = 0; m < MF; ++m) {
            long gr = brow + wr * (BM / MPOS) + m * 16 + 4 * lg;
#pragma unroll
            for (int r = 0; r < 4; ++r) {
                float v = acc[m][n][r] + bvs;
                if (ds) v *= qs;
                C[(gr + r) * (long)N + gc] = (OutT)v;
            }
        }
    }
}

// ============================================================================
// Sliding-window GQA flash attention, 8 waves/block = 4 heads x 2 q-groups
// (QBLK=64), tribuf counted vmcnt(2) (r12 measured).
// ============================================================================
__global__ __launch_bounds__(512) void attn_kernel(const bf16_t* __restrict__ QKV,
                                                   const bf16_t* __restrict__ Vtb,
                                                   bf16_t* __restrict__ Ob) {
    __shared__ bf16_t Kls[3][32 * 128];   // [j][d], chunk^=(row&7)
    __shared__ bf16_t Vls[3][128 * 32];   // [d][j], chunk^=((row^(row>>2))&3)
    __shared__ bf16_t Pls[8][32 * 40];    // per-wave P [q32][j40]

    const int wv   = threadIdx.x >> 6;    // 0..7
    const int lane = threadIdx.x & 63;
    const int lg = lane >> 4, lc = lane & 15;
    const int wg = wv >> 2;
    const int hh = wv & 3;

    const int swb = (blockIdx.x & 7) * 32 + (blockIdx.x >> 3);
    const int ti = swb & 31;
    const int g  = (swb >> 5) & 3;
    const int b  = swb >> 7;
    const int h  = g * 4 + hh;
    const int i0b = ti * 64;
    const int i0  = i0b + wg * 32;
    bf16_t* P = &Pls[wv][0];

    bf16x8 qf[2][4];
#pragma unroll
    for (int sq = 0; sq < 2; ++sq) {
        const bf16_t* qp = QKV + ((size_t)(b * SEQ) + i0 + sq * 16 + lc) * QKVN + h * HDIM + lg * 8;
#pragma unroll
        for (int kk = 0; kk < 4; ++kk) qf[sq][kk] = *(const bf16x8*)(qp + kk * 32);
    }

    auto stage = [&](int buf, int jb) {
        const bf16_t* kgb = QKV + ((size_t)(b * SEQ) + jb * 32) * QKVN + DIM + g * HDIM;
        {
            int row = wv * 4 + (lane >> 4);
            int ch  = (lane & 15) ^ (row & 7);
            async_copy16(kgb + (size_t)row * QKVN + ch * 8, &Kls[buf][wv * 512]);
        }
        const bf16_t* vgb = Vtb + (((size_t)(b * NKVH) + g) * 64 + jb) * 4096;
        {
            int row = wv * 16 + (lane >> 2);
            int ch  = (lane & 3) ^ ((row ^ (row >> 2)) & 3);
            async_copy16(vgb + row * 32 + ch * 8, &Vls[buf][wv * 512]);
        }
    };

    float m_run[2] = {-1e30f, -1e30f}, l_run[2] = {0.f, 0.f};
    f32x4 oacc[2][8] = {};

    int jlo = i0b - (WINSZ - 1); if (jlo < 0) jlo = 0;
    const int jb0 = jlo >> 5;
    const int jb1 = (i0b + 63) >> 5;

    stage(0, jb0);
    if (jb0 + 1 <= jb1) stage(1, jb0 + 1);

    for (int jb = jb0; jb <= jb1; ++jb) {
        const int j0 = jb * 32;
        const int it = jb - jb0;
        const int cur = it % 3;
        if (jb < jb1) asm volatile("s_waitcnt vmcnt(2)" ::: "memory");
        else          asm volatile("s_waitcnt vmcnt(0)" ::: "memory");
        __builtin_amdgcn_s_barrier();
        asm volatile("" ::: "memory");

        bf16x8 kf[2][4];
#pragma unroll
        for (int t = 0; t < 2; ++t)
#pragma unroll
            for (int kk = 0; kk < 4; ++kk) {
                int row = t * 16 + lc;
                int ch  = (kk * 4 + lg) ^ (row & 7);
                kf[t][kk] = *(const bf16x8*)(&Kls[cur][row * 128 + ch * 8]);
            }
        if (jb + 2 <= jb1) stage((it + 2) % 3, jb + 2);
        asm volatile("s_waitcnt lgkmcnt(0)" ::: "memory");
        __builtin_amdgcn_sched_barrier(0);

        f32x4 s[2][2];
        __builtin_amdgcn_s_setprio(1);
#pragma unroll
        for (int t = 0; t < 2; ++t)
#pragma unroll
            for (int sq = 0; sq < 2; ++sq) {
                f32x4 sv = {};
#pragma unroll
                for (int kk = 0; kk < 4; ++kk)
                    sv = __builtin_amdgcn_mfma_f32_16x16x32_bf16(kf[t][kk], qf[sq][kk], sv, 0, 0, 0);
                s[t][sq] = sv;
            }
        __builtin_amdgcn_s_setprio(0);

        const bool edge = (j0 < i0 - (WINSZ - 32)) || (j0 > i0 - 31);
        if (edge) {
#pragma unroll
            for (int t = 0; t < 2; ++t)
#pragma unroll
                for (int sq = 0; sq < 2; ++sq) {
                    int irow = i0 + sq * 16 + lc;
#pragma unroll
                    for (int r = 0; r < 4; ++r) {
                        int j = j0 + t * 16 + 4 * lg + r;
                        if (j > irow || j < irow - (WINSZ - 1)) s[t][sq][r] = -1e30f;
                    }
                }
        }
        float tmax[2];
#pragma unroll
        for (int sq = 0; sq < 2; ++sq) {
            float tm = fmaxf(fmaxf(fmaxf(s[0][sq][0], s[0][sq][1]), fmaxf(s[0][sq][2], s[0][sq][3])),
                             fmaxf(fmaxf(s[1][sq][0], s[1][sq][1]), fmaxf(s[1][sq][2], s[1][sq][3])));
            tm = fmaxf(tm, __shfl_xor(tm, 16, 64));
            tm = fmaxf(tm, __shfl_xor(tm, 32, 64));
            tmax[sq] = tm;
        }
        if (!__all(tmax[0] - m_run[0] <= 8.0f && tmax[1] - m_run[1] <= 8.0f)) {
#pragma unroll
            for (int sq = 0; sq < 2; ++sq) {
                float m_new = fmaxf(m_run[sq], tmax[sq]);
                float resc = __builtin_amdgcn_exp2f(m_run[sq] - m_new);
                l_run[sq] *= resc;
#pragma unroll
                for (int c = 0; c < 8; ++c) {
                    oacc[sq][c][0] *= resc; oacc[sq][c][1] *= resc;
                    oacc[sq][c][2] *= resc; oacc[sq][c][3] *= resc;
                }
                m_run[sq] = m_new;
            }
        }
        float psum[2] = {0.f, 0.f};
#pragma unroll
        for (int t = 0; t < 2; ++t)
#pragma unroll
            for (int sq = 0; sq < 2; ++sq) {
                bf16x4 pk;
#pragma unroll
                for (int r = 0; r < 4; ++r) {
                    float sv = s[t][sq][r];
                    float p = (edge && sv < -5e29f) ? 0.f : __builtin_amdgcn_exp2f(sv - m_run[sq]);
                    psum[sq] += p;
                    pk[r] = (bf16_t)p;
                }
                *(bf16x4*)(P + (sq * 16 + lc) * 40 + t * 16 + lg * 4) = pk;
            }
#pragma unroll
        for (int sq = 0; sq < 2; ++sq) {
            float ps = psum[sq];
            ps += __shfl_xor(ps, 16, 64);
            ps += __shfl_xor(ps, 32, 64);
            l_run[sq] += ps;
        }
        asm volatile("" ::: "memory");

        bf16x8 vf[8];
#pragma unroll
        for (int c = 0; c < 8; ++c) {
            int row = c * 16 + lc;
            int ch  = lg ^ ((row ^ (row >> 2)) & 3);
            vf[c] = *(const bf16x8*)(&Vls[cur][row * 32 + ch * 8]);
        }
        bf16x8 pf[2];
#pragma unroll
        for (int sq = 0; sq < 2; ++sq)
            pf[sq] = *(const bf16x8*)(P + (sq * 16 + lc) * 40 + lg * 8);

        __builtin_amdgcn_s_setprio(1);
#pragma unroll
        for (int c = 0; c < 8; ++c)
#pragma unroll
            for (int sq = 0; sq < 2; ++sq)
                oacc[sq][c] = __builtin_amdgcn_mfma_f32_16x16x32_bf16(vf[c], pf[sq], oacc[sq][c], 0, 0, 0);
        __builtin_amdgcn_s_setprio(0);
    }

#pragma unroll
    for (int sq = 0; sq < 2; ++sq) {
        const float inv = 1.f / l_run[sq];
#pragma unroll
        for (int c = 0; c < 8; ++c) {
            bf16x4 ov;
#pragma unroll
            for (int r = 0; r < 4; ++r) ov[r] = (bf16_t)(oacc[sq][c][r] * inv);
            *(bf16x4*)(Ob + ((size_t)(b * SEQ) + i0 + sq * 16 + lc) * DIM + h * HDIM + c * 16 + lg * 4) = ov;
        }
    }
}

extern "C" void kernel_launch(void* const* d_in, const int* in_sizes, int n_in,
                              void* d_out, int out_size, void* d_ws, size_t ws_size,
                              hipStream_t stream) {
    const float* x  = (const float*)d_in[0];
    const float* Wq = (const float*)d_in[1];
    const float* bq = (const float*)d_in[2];
    const float* Wk = (const float*)d_in[3];
    const float* bk = (const float*)d_in[4];
    const float* Wv = (const float*)d_in[5];
    const float* bv = (const float*)d_in[6];
    const float* Wo = (const float*)d_in[7];
    const float* bo = (const float*)d_in[8];
    float* out = (float*)d_out;

    char* ws = (char*)d_ws;
    bf16_t* xb    = (bf16_t*)(ws);                       // 16 MB  (later aliased as Ob)
    bf16_t* WqkvT = (bf16_t*)(ws + (16u << 20));         // 12 MB
    bf16_t* WoT   = (bf16_t*)(ws + (28u << 20));         //  8 MB
    bf16_t* QKVb  = (bf16_t*)(ws + (36u << 20));         // 24 MB (V region unused)
    float*  bqkv  = (float*) (ws + (60u << 20));         // 12 KB
    bf16_t* Vtb   = (bf16_t*)(ws + (61u << 20));         //  4 MB blocked V^T
    bf16_t* Ob    = xb;

    const float qs = 0.12751707498038074f;   // 1/sqrt(128) * log2(e)

    preprocess<<<18444, 256, 0, stream>>>(x, Wq, bq, Wk, bk, Wv, bv, Wo,
                                          xb, WqkvT, WoT, bqkv);

    // fused QKV projection: 256x192 tiles, 1 barrier/K-tile, dbuf (r10 best)
    gemm1b<256, 192, 4, bf16_t, true><<<dim3((MROWS / 256) * (QKVN / 192)), 512, 0, stream>>>(
        xb, WqkvT, bqkv, QKVb, Vtb, MROWS, QKVN, DIM, qs, DIM);

    attn_kernel<<<dim3(NB * NKVH * (SEQ / 64)), 512, 0, stream>>>(QKVb, Vtb, Ob);

    // output projection: 128x256 tiles, 1 barrier/K-tile, tribuf counted vmcnt
    gemm1b3<128, 256, 2, float><<<dim3((MROWS / 128) * (DIM / 256)), 512, 0, stream>>>(
        Ob, WoT, bo, out, MROWS, DIM, DIM, 1.0f, 0);
}